// Round 2
// 708.129 us; speedup vs baseline: 1.0385x; 1.0385x over previous
//
#include <hip/hip_runtime.h>
#include <hip/hip_bf16.h>
#include <math.h>

#define N_S   512
#define C_S   2048
#define HW_S  128
#define NCLS  751
#define NCLSP 768           // padded to 12*64 for the MFMA GEMM
#define ALPHA 1.2f
#define LAMB  0.5f
#define SIGMA 0.8f
#define BN_EPS 1e-5f
#define KSPLIT 4
#define KSEG  (C_S / KSPLIT)        // 512

typedef __attribute__((ext_vector_type(8))) short short8;   // 8 bf16 = 4 VGPRs
typedef __attribute__((ext_vector_type(4))) float f32x4;

__device__ __forceinline__ unsigned short f2bf(float x) {
    __hip_bfloat16 h = __float2bfloat16(x);
    return *reinterpret_cast<unsigned short*>(&h);
}

// -------------------------------------------------------------- 1. avg pool
// features [N, C, H, W] -> gf (= d_out+1). 8 lanes per (n,c) pair, 4 float4/lane.
// Read-once stream -> nontemporal loads (keep L2 for gemm operands).
// NOTE: __builtin_nontemporal_load needs a clang ext_vector_type, not
// HIP_vector_type float4 -> use f32x4.
// Block 0 zero-inits the 8 control words (accum + finalize ctr).
__global__ __launch_bounds__(256) void pool_kernel(const float* __restrict__ feat,
                                                   float* __restrict__ out_gf,
                                                   float* __restrict__ ctrl) {
    if (blockIdx.x == 0 && threadIdx.x < 8) ctrl[threadIdx.x] = 0.0f;
    int pair = blockIdx.x * 32 + (threadIdx.x >> 3);   // n*C + c
    int sub  = threadIdx.x & 7;
    const f32x4* p = reinterpret_cast<const f32x4*>(feat + (size_t)pair * HW_S);
    f32x4 v0 = __builtin_nontemporal_load(p + sub);
    f32x4 v1 = __builtin_nontemporal_load(p + sub + 8);
    f32x4 v2 = __builtin_nontemporal_load(p + sub + 16);
    f32x4 v3 = __builtin_nontemporal_load(p + sub + 24);
    float s = (v0[0] + v0[1] + v0[2] + v0[3]) + (v1[0] + v1[1] + v1[2] + v1[3])
            + (v2[0] + v2[1] + v2[2] + v2[3]) + (v3[0] + v3[1] + v3[2] + v3[3]);
    #pragma unroll
    for (int off = 4; off > 0; off >>= 1) s += __shfl_down(s, off, 8);
    if (sub == 0) out_gf[pair] = s * (1.0f / HW_S);
}

// -------------------------------------------------------------- 2. BN stats
__global__ __launch_bounds__(256) void meanvar_kernel(const float* __restrict__ gf,
                                                      const float* __restrict__ gamma,
                                                      float* __restrict__ mu_out,
                                                      float* __restrict__ scale_out) {
    int tc = threadIdx.x & 31;      // channel within block
    int tr = threadIdx.x >> 5;      // 0..7 row group
    int c  = blockIdx.x * 32 + tc;
    const float* col = gf + c;
    float sum = 0.f, sumsq = 0.f;
    #pragma unroll 4
    for (int n = tr * 64; n < tr * 64 + 64; ++n) {
        float x = col[(size_t)n * C_S];
        sum += x; sumsq += x * x;
    }
    __shared__ float s1[8][32], s2[8][32];
    s1[tr][tc] = sum; s2[tr][tc] = sumsq;
    __syncthreads();
    if (threadIdx.x < 32) {
        int cc = blockIdx.x * 32 + threadIdx.x;
        float a = 0.f, b = 0.f;
        #pragma unroll
        for (int r = 0; r < 8; ++r) { a += s1[r][threadIdx.x]; b += s2[r][threadIdx.x]; }
        float mu  = a * (1.0f / N_S);
        float var = b * (1.0f / N_S) - mu * mu;
        mu_out[cc]    = mu;
        scale_out[cc] = gamma[cc] / sqrtf(var + BN_EPS);
    }
}

// ------------------- 3. fused BN-apply+l2norm (blocks 0..511) / wnorm (512..1279)
__global__ __launch_bounds__(256) void norm_kernel(const float* __restrict__ gf,
                                                   const float* __restrict__ mu,
                                                   const float* __restrict__ scale,
                                                   const float* __restrict__ w,
                                                   unsigned short* __restrict__ bnnh,
                                                   unsigned short* __restrict__ wnh,
                                                   float* __restrict__ sq) {
    int b = blockIdx.x, t = threadIdx.x;
    __shared__ float red[4];
    __shared__ float sinv;
    if (b < N_S) {
        int n = b;
        const float* row = gf + (size_t)n * C_S;
        float v[8]; float ss = 0.f;
        #pragma unroll
        for (int k = 0; k < 8; ++k) {
            int c = t + k * 256;
            float x = (row[c] - mu[c]) * scale[c];
            v[k] = x; ss += x * x;
        }
        #pragma unroll
        for (int off = 32; off > 0; off >>= 1) ss += __shfl_down(ss, off, 64);
        if ((t & 63) == 0) red[t >> 6] = ss;
        __syncthreads();
        if (t == 0) {
            float tot = red[0] + red[1] + red[2] + red[3];
            float inv = 1.0f / fmaxf(sqrtf(tot), 1e-12f);
            sinv = inv;
            sq[n] = tot * inv * inv;
        }
        __syncthreads();
        float inv = sinv;
        unsigned short* orow = bnnh + (size_t)n * C_S;
        #pragma unroll
        for (int k = 0; k < 8; ++k) orow[t + k * 256] = f2bf(v[k] * inv);
    } else {
        int r = b - N_S;                 // 0..767
        unsigned short* orow = wnh + (size_t)r * C_S;
        if (r >= NCLS) {                 // zero padding rows 751..767
            #pragma unroll
            for (int k = 0; k < 8; ++k) orow[t + k * 256] = 0;
            return;
        }
        const float* row = w + (size_t)r * C_S;
        float v[8]; float ss = 0.f;
        #pragma unroll
        for (int k = 0; k < 8; ++k) {
            float x = row[t + k * 256];
            v[k] = x; ss += x * x;
        }
        #pragma unroll
        for (int off = 32; off > 0; off >>= 1) ss += __shfl_down(ss, off, 64);
        if ((t & 63) == 0) red[t >> 6] = ss;
        __syncthreads();
        if (t == 0) sinv = 1.0f / fmaxf(sqrtf(red[0]+red[1]+red[2]+red[3]), 1e-12f);
        __syncthreads();
        float inv = sinv;
        #pragma unroll
        for (int k = 0; k < 8; ++k) orow[t + k * 256] = f2bf(v[k] * inv);
    }
}

// --------------- 4. merged K-split MFMA GEMMs -> fp32 partials
// gid in [0,2560): gid<1536 -> logits tiles (384 tiles x 4 ksplits),
//                  else     -> Gram tiles  (256 tiles x 4 ksplits).
// Each wave: 16x64 output tile over K=512 segment, writes partial[ks].
// unroll 4 -> 20 independent 16B loads in flight before the first waitcnt,
// hiding L2 latency at ~2.5 waves/SIMD occupancy.
__global__ __launch_bounds__(256) void gemm_kernel(const unsigned short* __restrict__ bnnh,
                                                   const unsigned short* __restrict__ wnh,
                                                   float* __restrict__ logits_p,   // [4][512*768]
                                                   float* __restrict__ G_p) {      // [4][512*512]
    int wave = threadIdx.x >> 6, lane = threadIdx.x & 63;
    int gid = blockIdx.x * 4 + wave;
    const unsigned short* Bh; float* Cm; int m0, n0, ldc, ks;
    if (gid < 1536) {
        int tile = gid >> 2; ks = gid & 3;
        Bh = wnh; m0 = (tile & 31) * 16; n0 = (tile >> 5) * 64; ldc = NCLSP;
        Cm = logits_p + (size_t)ks * (N_S * NCLSP);
    } else {
        int g2 = gid - 1536;
        int tile = g2 >> 2; ks = g2 & 3;
        Bh = bnnh; m0 = (tile & 31) * 16; n0 = (tile >> 5) * 64; ldc = N_S;
        Cm = G_p + (size_t)ks * (N_S * N_S);
    }
    int kbase = ks * KSEG;
    int mrow = m0 + (lane & 15);
    int kq   = (lane >> 4) * 8;
    f32x4 acc0 = {0,0,0,0}, acc1 = {0,0,0,0}, acc2 = {0,0,0,0}, acc3 = {0,0,0,0};
    const unsigned short* arow = bnnh + (size_t)mrow * C_S + kbase + kq;
    const unsigned short* brow = Bh + (size_t)(n0 + (lane & 15)) * C_S + kbase + kq;
    #pragma unroll 4
    for (int k = 0; k < KSEG; k += 32) {
        short8 a  = *reinterpret_cast<const short8*>(arow + k);
        short8 b0 = *reinterpret_cast<const short8*>(brow + k);
        short8 b1 = *reinterpret_cast<const short8*>(brow + 16 * C_S + k);
        short8 b2 = *reinterpret_cast<const short8*>(brow + 32 * C_S + k);
        short8 b3 = *reinterpret_cast<const short8*>(brow + 48 * C_S + k);
        acc0 = __builtin_amdgcn_mfma_f32_16x16x32_bf16(a, b0, acc0, 0, 0, 0);
        acc1 = __builtin_amdgcn_mfma_f32_16x16x32_bf16(a, b1, acc1, 0, 0, 0);
        acc2 = __builtin_amdgcn_mfma_f32_16x16x32_bf16(a, b2, acc2, 0, 0, 0);
        acc3 = __builtin_amdgcn_mfma_f32_16x16x32_bf16(a, b3, acc3, 0, 0, 0);
    }
    int ccol  = lane & 15;
    int crow0 = m0 + (lane >> 4) * 4;
    #pragma unroll
    for (int r = 0; r < 4; ++r) {
        float* orow = Cm + (size_t)(crow0 + r) * ldc + n0 + ccol;
        orow[0]  = acc0[r];
        orow[16] = acc1[r];
        orow[32] = acc2[r];
        orow[48] = acc3[r];
    }
}

// ---------------------------------------------- 5. softmax -> atten[n]
// Single read pass: float4-vectorized sum of the 4 K-split partials held in
// registers; reused for max-reduce, sum-reduce and the target-class pick.
// Threads 0..191 each own one float4 (4 classes); pad classes masked to -1e30.
__global__ __launch_bounds__(256) void softmax_atten_kernel(const float* __restrict__ logits_p,
                                                            const int* __restrict__ targets,
                                                            float* __restrict__ atten) {
    int n = blockIdx.x, t = threadIdx.x;
    const f32x4* r0 = reinterpret_cast<const f32x4*>(logits_p + (size_t)n * NCLSP);
    const f32x4* r1 = r0 + (size_t)(N_S * NCLSP) / 4;
    const f32x4* r2 = r1 + (size_t)(N_S * NCLSP) / 4;
    const f32x4* r3 = r2 + (size_t)(N_S * NCLSP) / 4;
    __shared__ float red[4];
    __shared__ float srmax, srsum, stgt;
    const bool has = (t < NCLSP / 4);          // 192 active threads
    f32x4 v = {-1e30f, -1e30f, -1e30f, -1e30f};
    float m = -1e30f;
    if (has) {
        f32x4 a = r0[t], b = r1[t], c = r2[t], d = r3[t];
        v = a + b + c + d;
        int base = t * 4;
        if (base + 0 >= NCLS) v[0] = -1e30f;
        if (base + 1 >= NCLS) v[1] = -1e30f;
        if (base + 2 >= NCLS) v[2] = -1e30f;
        if (base + 3 >= NCLS) v[3] = -1e30f;
        m = fmaxf(fmaxf(v[0], v[1]), fmaxf(v[2], v[3]));
    }
    #pragma unroll
    for (int off = 32; off > 0; off >>= 1) m = fmaxf(m, __shfl_down(m, off, 64));
    if ((t & 63) == 0) red[t >> 6] = m;
    __syncthreads();
    if (t == 0) srmax = fmaxf(fmaxf(red[0], red[1]), fmaxf(red[2], red[3]));
    __syncthreads();
    float rm = srmax;
    int tg = targets[n];
    float s = 0.f;
    if (has) {
        float ex = expf(v[0] - rm);
        float ey = expf(v[1] - rm);
        float ez = expf(v[2] - rm);
        float ew = expf(v[3] - rm);
        s = ex + ey + ez + ew;                  // masked elems -> exp(-huge) = 0
        if (t == (tg >> 2)) {
            int e = tg & 3;
            stgt = (e == 0) ? ex : (e == 1) ? ey : (e == 2) ? ez : ew;
        }
    }
    #pragma unroll
    for (int off = 32; off > 0; off >>= 1) s += __shfl_down(s, off, 64);
    if ((t & 63) == 0) red[t >> 6] = s;
    __syncthreads();
    if (t == 0) {
        srsum = red[0] + red[1] + red[2] + red[3];
        atten[n] = stgt / srsum;
    }
}

// ------------------------ 6. pairwise loss reduction + fused finalize
// float4-vectorized: each thread owns exactly 4 consecutive j of one row i
// (65536 threads * 4 = 512*512 pairs; no loop).
// ctrl[0..3] = {numP, denP, numN, denN}; ctrl[4] (as uint) = completion ctr.
__global__ __launch_bounds__(256) void pair_reduce_kernel(const float* __restrict__ G_p,
                                                          const float* __restrict__ sq,
                                                          const float* __restrict__ atten,
                                                          const int* __restrict__ targets,
                                                          float* __restrict__ ctrl,
                                                          float* __restrict__ out) {
    float numP = 0.f, denP = 0.f, numN = 0.f, denN = 0.f;
    const float inv_sig2 = 1.0f / (SIGMA * SIGMA);
    int g  = blockIdx.x * 256 + threadIdx.x;     // 0..65535
    int i  = g >> 7;                             // row 0..511
    int j0 = (g & 127) * 4;                      // col group
    size_t p = (size_t)i * N_S + j0;
    const f32x4* G0 = reinterpret_cast<const f32x4*>(G_p + p);
    const f32x4* G1 = reinterpret_cast<const f32x4*>(G_p + N_S * N_S + p);
    const f32x4* G2 = reinterpret_cast<const f32x4*>(G_p + 2 * N_S * N_S + p);
    const f32x4* G3 = reinterpret_cast<const f32x4*>(G_p + 3 * N_S * N_S + p);
    f32x4 gsumv = *G0 + *G1 + *G2 + *G3;
    float gsum[4] = { gsumv[0], gsumv[1], gsumv[2], gsumv[3] };
    f32x4 sqjv = *reinterpret_cast<const f32x4*>(sq + j0);
    float sqj[4] = { sqjv[0], sqjv[1], sqjv[2], sqjv[3] };
    f32x4 ajv = *reinterpret_cast<const f32x4*>(atten + j0);
    float aj[4] = { ajv[0], ajv[1], ajv[2], ajv[3] };
    int4 tjv = *reinterpret_cast<const int4*>(targets + j0);
    int tj[4] = { tjv.x, tjv.y, tjv.z, tjv.w };
    float sqi = sq[i];
    float ai  = atten[i];
    int   ti  = targets[i];
    #pragma unroll
    for (int e = 0; e < 4; ++e) {
        if (i == j0 + e) continue;               // off-diagonal mask
        float d2   = fmaxf(sqi + sqj[e] - 2.0f * gsum[e], 1e-12f);
        float dist = sqrtf(d2);
        float sneg = fmaxf(ALPHA - dist, 1e-12f);
        float Aij  = fminf(ai, aj[e]);
        if (ti == tj[e]) {
            float Wm = expf(-d2 * inv_sig2) * Aij;
            numP += Wm * d2; denP += Wm;
        } else {
            float Wm = sneg * Aij;
            numN += Wm * sneg * sneg; denN += Wm;
        }
    }
    #pragma unroll
    for (int off = 32; off > 0; off >>= 1) {
        numP += __shfl_down(numP, off, 64);
        denP += __shfl_down(denP, off, 64);
        numN += __shfl_down(numN, off, 64);
        denN += __shfl_down(denN, off, 64);
    }
    __shared__ float red[4][4];
    int t = threadIdx.x;
    if ((t & 63) == 0) {
        int w = t >> 6;
        red[w][0] = numP; red[w][1] = denP; red[w][2] = numN; red[w][3] = denN;
    }
    __syncthreads();
    if (t < 4) {
        float s = red[0][t] + red[1][t] + red[2][t] + red[3][t];
        atomicAdd(&ctrl[t], s);
    }
    __syncthreads();
    if (t == 0) {
        __threadfence();
        unsigned prev = atomicAdd(reinterpret_cast<unsigned*>(ctrl + 4), 1u);
        if (prev == gridDim.x - 1) {   // last block: finalize
            float a0 = atomicAdd(&ctrl[0], 0.0f);
            float a1 = atomicAdd(&ctrl[1], 0.0f);
            float a2 = atomicAdd(&ctrl[2], 0.0f);
            float a3 = atomicAdd(&ctrl[3], 0.0f);
            float L_P = 0.5f * a0 / a1;
            float L_N = 0.5f * a2 / a3;
            out[0] = (1.0f - LAMB) * L_P + LAMB * L_N;
        }
    }
}

// ---------------------------------------------------------------- launcher
extern "C" void kernel_launch(void* const* d_in, const int* in_sizes, int n_in,
                              void* d_out, int out_size, void* d_ws, size_t ws_size,
                              hipStream_t stream) {
    const float* features = (const float*)d_in[0];
    const int*   targets  = (const int*)d_in[1];
    const float* gamma    = (const float*)d_in[2];
    const float* weight   = (const float*)d_in[3];
    float* out = (float*)d_out;
    float* gf  = out + 1;                    // global_feat lives in d_out directly

    // workspace layout (element offsets; bf16 arrays 16B-aligned)
    float* ws       = (float*)d_ws;
    float* mu       = ws;                        // 2048
    float* scale    = mu + 2048;                 // 2048
    float* sq       = scale + 2048;              // 512
    float* atten    = sq + 512;                  // 512
    float* ctrl     = atten + 512;               // 16: [0..3] sums, [4] ctr
    float* logits_p = ctrl + 16;                 // 4 * 512*768 = 1572864
    float* G_p      = logits_p + 4 * (N_S * NCLSP);  // 4 * 512*512 = 1048576
    unsigned short* bnnh = (unsigned short*)(G_p + 4 * (N_S * N_S));  // 512*2048 bf16
    unsigned short* wnh  = bnnh + (size_t)N_S * C_S;                  // 768*2048 bf16

    hipLaunchKernelGGL(pool_kernel, dim3((N_S * C_S) / 32), dim3(256), 0, stream,
                       features, gf, ctrl);
    hipLaunchKernelGGL(meanvar_kernel, dim3(C_S / 32), dim3(256), 0, stream,
                       gf, gamma, mu, scale);
    hipLaunchKernelGGL(norm_kernel, dim3(N_S + NCLSP), dim3(256), 0, stream,
                       gf, mu, scale, weight, bnnh, wnh, sq);
    hipLaunchKernelGGL(gemm_kernel, dim3(640), dim3(256), 0, stream,
                       bnnh, wnh, logits_p, G_p);
    hipLaunchKernelGGL(softmax_atten_kernel, dim3(N_S), dim3(256), 0, stream,
                       logits_p, targets, atten);
    hipLaunchKernelGGL(pair_reduce_kernel, dim3(256), dim3(256), 0, stream,
                       G_p, sq, atten, targets, ctrl, out);
}

// Round 3
// 706.635 us; speedup vs baseline: 1.0407x; 1.0021x over previous
//
#include <hip/hip_runtime.h>
#include <hip/hip_bf16.h>
#include <math.h>

#define N_S   512
#define C_S   2048
#define HW_S  128
#define NCLS  751
#define NCLSP 768           // padded to 12*64 for the MFMA GEMM
#define ALPHA 1.2f
#define LAMB  0.5f
#define SIGMA 0.8f
#define BN_EPS 1e-5f
#define KSPLIT 4
#define KSEG  (C_S / KSPLIT)        // 512

typedef __attribute__((ext_vector_type(8))) short short8;   // 8 bf16 = 4 VGPRs
typedef __attribute__((ext_vector_type(4))) float f32x4;

__device__ __forceinline__ unsigned short f2bf(float x) {
    __hip_bfloat16 h = __float2bfloat16(x);
    return *reinterpret_cast<unsigned short*>(&h);
}

// -------------------------------------------------------------- 1. avg pool
// features [N, C, H, W] -> gf (= d_out+1). 8 lanes per (n,c) pair, 4 f32x4/lane.
// Read-once stream -> nontemporal loads (keep L2 for gemm operands).
// Block 0 zero-inits the 8 control words (accum + finalize ctr).
__global__ __launch_bounds__(256) void pool_kernel(const float* __restrict__ feat,
                                                   float* __restrict__ out_gf,
                                                   float* __restrict__ ctrl) {
    if (blockIdx.x == 0 && threadIdx.x < 8) ctrl[threadIdx.x] = 0.0f;
    int pair = blockIdx.x * 32 + (threadIdx.x >> 3);   // n*C + c
    int sub  = threadIdx.x & 7;
    const f32x4* p = reinterpret_cast<const f32x4*>(feat + (size_t)pair * HW_S);
    f32x4 v0 = __builtin_nontemporal_load(p + sub);
    f32x4 v1 = __builtin_nontemporal_load(p + sub + 8);
    f32x4 v2 = __builtin_nontemporal_load(p + sub + 16);
    f32x4 v3 = __builtin_nontemporal_load(p + sub + 24);
    float s = (v0[0] + v0[1] + v0[2] + v0[3]) + (v1[0] + v1[1] + v1[2] + v1[3])
            + (v2[0] + v2[1] + v2[2] + v2[3]) + (v3[0] + v3[1] + v3[2] + v3[3]);
    #pragma unroll
    for (int off = 4; off > 0; off >>= 1) s += __shfl_down(s, off, 8);
    if (sub == 0) out_gf[pair] = s * (1.0f / HW_S);
}

// -------------------------------------------------------------- 2. BN stats
__global__ __launch_bounds__(256) void meanvar_kernel(const float* __restrict__ gf,
                                                      const float* __restrict__ gamma,
                                                      float* __restrict__ mu_out,
                                                      float* __restrict__ scale_out) {
    int tc = threadIdx.x & 31;      // channel within block
    int tr = threadIdx.x >> 5;      // 0..7 row group
    int c  = blockIdx.x * 32 + tc;
    const float* col = gf + c;
    float sum = 0.f, sumsq = 0.f;
    #pragma unroll 4
    for (int n = tr * 64; n < tr * 64 + 64; ++n) {
        float x = col[(size_t)n * C_S];
        sum += x; sumsq += x * x;
    }
    __shared__ float s1[8][32], s2[8][32];
    s1[tr][tc] = sum; s2[tr][tc] = sumsq;
    __syncthreads();
    if (threadIdx.x < 32) {
        int cc = blockIdx.x * 32 + threadIdx.x;
        float a = 0.f, b = 0.f;
        #pragma unroll
        for (int r = 0; r < 8; ++r) { a += s1[r][threadIdx.x]; b += s2[r][threadIdx.x]; }
        float mu  = a * (1.0f / N_S);
        float var = b * (1.0f / N_S) - mu * mu;
        mu_out[cc]    = mu;
        scale_out[cc] = gamma[cc] / sqrtf(var + BN_EPS);
    }
}

// ------------------- 3. fused BN-apply+l2norm (blocks 0..511) / wnorm (512..1279)
// Each thread owns 8 CONTIGUOUS channels: 2x f32x4 loads + one 16B bf16 store
// (replaces 8 scalar 2B stores).
__global__ __launch_bounds__(256) void norm_kernel(const float* __restrict__ gf,
                                                   const float* __restrict__ mu,
                                                   const float* __restrict__ scale,
                                                   const float* __restrict__ w,
                                                   unsigned short* __restrict__ bnnh,
                                                   unsigned short* __restrict__ wnh,
                                                   float* __restrict__ sq) {
    int b = blockIdx.x, t = threadIdx.x;
    __shared__ float red[4];
    __shared__ float sinv;
    if (b < N_S) {
        int n = b;
        const f32x4* rowv = reinterpret_cast<const f32x4*>(gf + (size_t)n * C_S + t * 8);
        const f32x4* muv  = reinterpret_cast<const f32x4*>(mu + t * 8);
        const f32x4* scv  = reinterpret_cast<const f32x4*>(scale + t * 8);
        f32x4 v0 = (rowv[0] - muv[0]) * scv[0];
        f32x4 v1 = (rowv[1] - muv[1]) * scv[1];
        float ss = v0[0]*v0[0] + v0[1]*v0[1] + v0[2]*v0[2] + v0[3]*v0[3]
                 + v1[0]*v1[0] + v1[1]*v1[1] + v1[2]*v1[2] + v1[3]*v1[3];
        #pragma unroll
        for (int off = 32; off > 0; off >>= 1) ss += __shfl_down(ss, off, 64);
        if ((t & 63) == 0) red[t >> 6] = ss;
        __syncthreads();
        if (t == 0) {
            float tot = red[0] + red[1] + red[2] + red[3];
            float inv = 1.0f / fmaxf(sqrtf(tot), 1e-12f);
            sinv = inv;
            sq[n] = tot * inv * inv;
        }
        __syncthreads();
        float inv = sinv;
        short8 o;
        #pragma unroll
        for (int k = 0; k < 4; ++k) o[k]     = (short)f2bf(v0[k] * inv);
        #pragma unroll
        for (int k = 0; k < 4; ++k) o[4 + k] = (short)f2bf(v1[k] * inv);
        *reinterpret_cast<short8*>(bnnh + (size_t)n * C_S + t * 8) = o;
    } else {
        int r = b - N_S;                 // 0..767
        if (r >= NCLS) {                 // zero padding rows 751..767
            short8 z = {0,0,0,0,0,0,0,0};
            *reinterpret_cast<short8*>(wnh + (size_t)r * C_S + t * 8) = z;
            return;
        }
        const f32x4* rowv = reinterpret_cast<const f32x4*>(w + (size_t)r * C_S + t * 8);
        f32x4 v0 = rowv[0], v1 = rowv[1];
        float ss = v0[0]*v0[0] + v0[1]*v0[1] + v0[2]*v0[2] + v0[3]*v0[3]
                 + v1[0]*v1[0] + v1[1]*v1[1] + v1[2]*v1[2] + v1[3]*v1[3];
        #pragma unroll
        for (int off = 32; off > 0; off >>= 1) ss += __shfl_down(ss, off, 64);
        if ((t & 63) == 0) red[t >> 6] = ss;
        __syncthreads();
        if (t == 0) sinv = 1.0f / fmaxf(sqrtf(red[0]+red[1]+red[2]+red[3]), 1e-12f);
        __syncthreads();
        float inv = sinv;
        short8 o;
        #pragma unroll
        for (int k = 0; k < 4; ++k) o[k]     = (short)f2bf(v0[k] * inv);
        #pragma unroll
        for (int k = 0; k < 4; ++k) o[4 + k] = (short)f2bf(v1[k] * inv);
        *reinterpret_cast<short8*>(wnh + (size_t)r * C_S + t * 8) = o;
    }
}

// --------------- 4. merged K-split MFMA GEMMs, in-block K-reduction
// One block per 16x64 output tile (640 blocks): blocks 0..383 -> logits,
// 384..639 -> Gram. The 4 waves of a block each compute one K=512 segment,
// partials are reduced in LDS and the FINAL C is written once (no fp32
// partial round-trip; downstream kernels read a single array).
__global__ __launch_bounds__(256) void gemm_kernel(const unsigned short* __restrict__ bnnh,
                                                   const unsigned short* __restrict__ wnh,
                                                   float* __restrict__ logits,   // [512*768]
                                                   float* __restrict__ G) {      // [512*512]
    int wave = threadIdx.x >> 6, lane = threadIdx.x & 63;
    int gid = blockIdx.x;
    const unsigned short* Bh; float* Cm; int m0, n0, ldc;
    if (gid < 384) {
        Bh = wnh; m0 = (gid & 31) * 16; n0 = (gid >> 5) * 64; ldc = NCLSP;
        Cm = logits;
    } else {
        int g2 = gid - 384;
        Bh = bnnh; m0 = (g2 & 31) * 16; n0 = (g2 >> 5) * 64; ldc = N_S;
        Cm = G;
    }
    int kbase = wave * KSEG;
    int mrow = m0 + (lane & 15);
    int kq   = (lane >> 4) * 8;
    f32x4 acc0 = {0,0,0,0}, acc1 = {0,0,0,0}, acc2 = {0,0,0,0}, acc3 = {0,0,0,0};
    const unsigned short* arow = bnnh + (size_t)mrow * C_S + kbase + kq;
    const unsigned short* brow = Bh + (size_t)(n0 + (lane & 15)) * C_S + kbase + kq;
    #pragma unroll 4
    for (int k = 0; k < KSEG; k += 32) {
        short8 a  = *reinterpret_cast<const short8*>(arow + k);
        short8 b0 = *reinterpret_cast<const short8*>(brow + k);
        short8 b1 = *reinterpret_cast<const short8*>(brow + 16 * C_S + k);
        short8 b2 = *reinterpret_cast<const short8*>(brow + 32 * C_S + k);
        short8 b3 = *reinterpret_cast<const short8*>(brow + 48 * C_S + k);
        acc0 = __builtin_amdgcn_mfma_f32_16x16x32_bf16(a, b0, acc0, 0, 0, 0);
        acc1 = __builtin_amdgcn_mfma_f32_16x16x32_bf16(a, b1, acc1, 0, 0, 0);
        acc2 = __builtin_amdgcn_mfma_f32_16x16x32_bf16(a, b2, acc2, 0, 0, 0);
        acc3 = __builtin_amdgcn_mfma_f32_16x16x32_bf16(a, b3, acc3, 0, 0, 0);
    }
    // ---- in-block reduction of the 4 K-segments ----
    // LDS tile layout: row-major 16x64, row stride 68 floats (2-way banks only).
    __shared__ float lds[4][16 * 68];
    int lrow = (lane >> 4) * 4;
    int lcol = lane & 15;
    #pragma unroll
    for (int r = 0; r < 4; ++r) {
        float* dst = &lds[wave][(lrow + r) * 68 + lcol];
        dst[0]  = acc0[r];
        dst[16] = acc1[r];
        dst[32] = acc2[r];
        dst[48] = acc3[r];
    }
    __syncthreads();
    int t   = threadIdx.x;
    int row = t >> 4;           // 0..15
    int col = (t & 15) * 4;     // 0..60, 16B aligned (68 floats = 17*16B)
    const f32x4* p0 = reinterpret_cast<const f32x4*>(&lds[0][row * 68 + col]);
    const f32x4* p1 = reinterpret_cast<const f32x4*>(&lds[1][row * 68 + col]);
    const f32x4* p2 = reinterpret_cast<const f32x4*>(&lds[2][row * 68 + col]);
    const f32x4* p3 = reinterpret_cast<const f32x4*>(&lds[3][row * 68 + col]);
    f32x4 s = *p0 + *p1 + *p2 + *p3;
    *reinterpret_cast<f32x4*>(Cm + (size_t)(m0 + row) * ldc + n0 + col) = s;
}

// ---------------------------------------------- 5. softmax -> atten[n]
// Single pass over the (already-reduced) logits row; one f32x4 per thread,
// reused for max-reduce, sum-reduce and the target-class pick.
__global__ __launch_bounds__(256) void softmax_atten_kernel(const float* __restrict__ logits,
                                                            const int* __restrict__ targets,
                                                            float* __restrict__ atten) {
    int n = blockIdx.x, t = threadIdx.x;
    const f32x4* r0 = reinterpret_cast<const f32x4*>(logits + (size_t)n * NCLSP);
    __shared__ float red[4];
    __shared__ float srmax, srsum, stgt;
    const bool has = (t < NCLSP / 4);          // 192 active threads
    f32x4 v = {-1e30f, -1e30f, -1e30f, -1e30f};
    float m = -1e30f;
    if (has) {
        v = r0[t];
        int base = t * 4;
        if (base + 0 >= NCLS) v[0] = -1e30f;
        if (base + 1 >= NCLS) v[1] = -1e30f;
        if (base + 2 >= NCLS) v[2] = -1e30f;
        if (base + 3 >= NCLS) v[3] = -1e30f;
        m = fmaxf(fmaxf(v[0], v[1]), fmaxf(v[2], v[3]));
    }
    #pragma unroll
    for (int off = 32; off > 0; off >>= 1) m = fmaxf(m, __shfl_down(m, off, 64));
    if ((t & 63) == 0) red[t >> 6] = m;
    __syncthreads();
    if (t == 0) srmax = fmaxf(fmaxf(red[0], red[1]), fmaxf(red[2], red[3]));
    __syncthreads();
    float rm = srmax;
    int tg = targets[n];
    float s = 0.f;
    if (has) {
        float ex = expf(v[0] - rm);
        float ey = expf(v[1] - rm);
        float ez = expf(v[2] - rm);
        float ew = expf(v[3] - rm);
        s = ex + ey + ez + ew;                  // masked elems -> exp(-huge) = 0
        if (t == (tg >> 2)) {
            int e = tg & 3;
            stgt = (e == 0) ? ex : (e == 1) ? ey : (e == 2) ? ez : ew;
        }
    }
    #pragma unroll
    for (int off = 32; off > 0; off >>= 1) s += __shfl_down(s, off, 64);
    if ((t & 63) == 0) red[t >> 6] = s;
    __syncthreads();
    if (t == 0) {
        srsum = red[0] + red[1] + red[2] + red[3];
        atten[n] = stgt / srsum;
    }
}

// ------------------------ 6. pairwise loss reduction + fused finalize
// Single f32x4 Gram load per thread (4 consecutive j of one row i).
// ctrl[0..3] = {numP, denP, numN, denN}; ctrl[4] (as uint) = completion ctr.
__global__ __launch_bounds__(256) void pair_reduce_kernel(const float* __restrict__ G,
                                                          const float* __restrict__ sq,
                                                          const float* __restrict__ atten,
                                                          const int* __restrict__ targets,
                                                          float* __restrict__ ctrl,
                                                          float* __restrict__ out) {
    float numP = 0.f, denP = 0.f, numN = 0.f, denN = 0.f;
    const float inv_sig2 = 1.0f / (SIGMA * SIGMA);
    int g  = blockIdx.x * 256 + threadIdx.x;     // 0..65535
    int i  = g >> 7;                             // row 0..511
    int j0 = (g & 127) * 4;                      // col group
    size_t p = (size_t)i * N_S + j0;
    f32x4 gsumv = *reinterpret_cast<const f32x4*>(G + p);
    float gsum[4] = { gsumv[0], gsumv[1], gsumv[2], gsumv[3] };
    f32x4 sqjv = *reinterpret_cast<const f32x4*>(sq + j0);
    float sqj[4] = { sqjv[0], sqjv[1], sqjv[2], sqjv[3] };
    f32x4 ajv = *reinterpret_cast<const f32x4*>(atten + j0);
    float aj[4] = { ajv[0], ajv[1], ajv[2], ajv[3] };
    int4 tjv = *reinterpret_cast<const int4*>(targets + j0);
    int tj[4] = { tjv.x, tjv.y, tjv.z, tjv.w };
    float sqi = sq[i];
    float ai  = atten[i];
    int   ti  = targets[i];
    #pragma unroll
    for (int e = 0; e < 4; ++e) {
        if (i == j0 + e) continue;               // off-diagonal mask
        float d2   = fmaxf(sqi + sqj[e] - 2.0f * gsum[e], 1e-12f);
        float dist = sqrtf(d2);
        float sneg = fmaxf(ALPHA - dist, 1e-12f);
        float Aij  = fminf(ai, aj[e]);
        if (ti == tj[e]) {
            float Wm = expf(-d2 * inv_sig2) * Aij;
            numP += Wm * d2; denP += Wm;
        } else {
            float Wm = sneg * Aij;
            numN += Wm * sneg * sneg; denN += Wm;
        }
    }
    #pragma unroll
    for (int off = 32; off > 0; off >>= 1) {
        numP += __shfl_down(numP, off, 64);
        denP += __shfl_down(denP, off, 64);
        numN += __shfl_down(numN, off, 64);
        denN += __shfl_down(denN, off, 64);
    }
    __shared__ float red[4][4];
    int t = threadIdx.x;
    if ((t & 63) == 0) {
        int w = t >> 6;
        red[w][0] = numP; red[w][1] = denP; red[w][2] = numN; red[w][3] = denN;
    }
    __syncthreads();
    if (t < 4) {
        float s = red[0][t] + red[1][t] + red[2][t] + red[3][t];
        atomicAdd(&ctrl[t], s);
    }
    __syncthreads();
    if (t == 0) {
        __threadfence();
        unsigned prev = atomicAdd(reinterpret_cast<unsigned*>(ctrl + 4), 1u);
        if (prev == gridDim.x - 1) {   // last block: finalize
            float a0 = atomicAdd(&ctrl[0], 0.0f);
            float a1 = atomicAdd(&ctrl[1], 0.0f);
            float a2 = atomicAdd(&ctrl[2], 0.0f);
            float a3 = atomicAdd(&ctrl[3], 0.0f);
            float L_P = 0.5f * a0 / a1;
            float L_N = 0.5f * a2 / a3;
            out[0] = (1.0f - LAMB) * L_P + LAMB * L_N;
        }
    }
}

// ---------------------------------------------------------------- launcher
extern "C" void kernel_launch(void* const* d_in, const int* in_sizes, int n_in,
                              void* d_out, int out_size, void* d_ws, size_t ws_size,
                              hipStream_t stream) {
    const float* features = (const float*)d_in[0];
    const int*   targets  = (const int*)d_in[1];
    const float* gamma    = (const float*)d_in[2];
    const float* weight   = (const float*)d_in[3];
    float* out = (float*)d_out;
    float* gf  = out + 1;                    // global_feat lives in d_out directly

    // workspace layout (element offsets; bf16 arrays 16B-aligned)
    float* ws     = (float*)d_ws;
    float* mu     = ws;                          // 2048
    float* scale  = mu + 2048;                   // 2048
    float* sq     = scale + 2048;                // 512
    float* atten  = sq + 512;                    // 512
    float* ctrl   = atten + 512;                 // 16: [0..3] sums, [4] ctr
    float* logits = ctrl + 16;                   // 512*768 = 393216
    float* G      = logits + (size_t)N_S * NCLSP;    // 512*512 = 262144
    unsigned short* bnnh = (unsigned short*)(G + (size_t)N_S * N_S);  // 512*2048 bf16
    unsigned short* wnh  = bnnh + (size_t)N_S * C_S;                  // 768*2048 bf16

    hipLaunchKernelGGL(pool_kernel, dim3((N_S * C_S) / 32), dim3(256), 0, stream,
                       features, gf, ctrl);
    hipLaunchKernelGGL(meanvar_kernel, dim3(C_S / 32), dim3(256), 0, stream,
                       gf, gamma, mu, scale);
    hipLaunchKernelGGL(norm_kernel, dim3(N_S + NCLSP), dim3(256), 0, stream,
                       gf, mu, scale, weight, bnnh, wnh, sq);
    hipLaunchKernelGGL(gemm_kernel, dim3(640), dim3(256), 0, stream,
                       bnnh, wnh, logits, G);
    hipLaunchKernelGGL(softmax_atten_kernel, dim3(N_S), dim3(256), 0, stream,
                       logits, targets, atten);
    hipLaunchKernelGGL(pair_reduce_kernel, dim3(256), dim3(256), 0, stream,
                       G, sq, atten, targets, ctrl, out);
}